// Round 5
// baseline (915.513 us; speedup 1.0000x reference)
//
#include <hip/hip_runtime.h>
#include <math.h>

#define F_IN 512
#define HDIM 16
#define CDIM 7
#define NBLK 1024          // partition blocks for p2a/p2b
#define BSH  8             // 256 nodes per bucket
#define NPB  (1 << BSH)
#define BMASK ((1u << BSH) - 1u)

// ---------------------------------------------- pass 2a: coarse histogram ----
// hist_g[bucket][blk] = #edges of this block with dst in bucket
__global__ __launch_bounds__(512) void k_p2a(const int* __restrict__ dst,
                                             unsigned* __restrict__ hist_g,
                                             int E, int nbuck) {
    __shared__ unsigned lh[512];
    int blk = blockIdx.x;
    int t = threadIdx.x;
    lh[t] = 0u;
    __syncthreads();
    int per = (E + NBLK - 1) / NBLK;
    int s0 = blk * per;
    int e0 = min(E, s0 + per);
    for (int i = s0 + t; i < e0; i += 512)
        atomicAdd(&lh[((unsigned)dst[i]) >> BSH], 1u);
    __syncthreads();
    if (t < nbuck) hist_g[(size_t)t * NBLK + blk] = lh[t];
}

// ------------------------- scan within each bucket over the 1024 blocks ----
__global__ __launch_bounds__(256) void k_scan_buckets(unsigned* __restrict__ hist_g,
                                                      unsigned* __restrict__ count) {
    __shared__ unsigned s[256];
    int b = blockIdx.x;
    int t = threadIdx.x;
    unsigned* row = hist_g + (size_t)b * NBLK;
    unsigned h[4];
#pragma unroll
    for (int j = 0; j < 4; ++j) h[j] = row[4 * t + j];
    unsigned p = h[0] + h[1] + h[2] + h[3];
    s[t] = p;
    __syncthreads();
    for (int off = 1; off < 256; off <<= 1) {
        unsigned u = (t >= off) ? s[t - off] : 0u;
        __syncthreads();
        s[t] += u;
        __syncthreads();
    }
    unsigned run = s[t] - p;
#pragma unroll
    for (int j = 0; j < 4; ++j) { unsigned hh = h[j]; row[4 * t + j] = run; run += hh; }
    if (t == 255) count[b] = run;
}

// ------------------------------------ exclusive scan of bucket totals ----
__global__ __launch_bounds__(512) void k_scan_tot(const unsigned* __restrict__ count,
                                                  unsigned* __restrict__ boff, int nbuck) {
    __shared__ unsigned s[512];
    int t = threadIdx.x;
    unsigned v = (t < nbuck) ? count[t] : 0u;
    s[t] = v;
    __syncthreads();
    for (int off = 1; off < 512; off <<= 1) {
        unsigned u = (t >= off) ? s[t - off] : 0u;
        __syncthreads();
        s[t] += u;
        __syncthreads();
    }
    if (t < nbuck) boff[t] = s[t] - v;
}

// --------------------- pass 2b: scatter packed pairs into bucket regions ----
__global__ __launch_bounds__(256) void k_p2b(const int* __restrict__ src,
                                             const int* __restrict__ dst,
                                             const unsigned* __restrict__ hist_g, // bases now
                                             const unsigned* __restrict__ boff,
                                             unsigned* __restrict__ pairs,
                                             int E, int nbuck) {
    __shared__ unsigned basel[512];
    __shared__ unsigned cnt[512];
    int blk = blockIdx.x;
    int t = threadIdx.x;
    for (int i = t; i < nbuck; i += 256) {
        basel[i] = hist_g[(size_t)i * NBLK + blk] + boff[i];
        cnt[i] = 0u;
    }
    __syncthreads();
    int per = (E + NBLK - 1) / NBLK;
    int s0 = blk * per;
    int e0 = min(E, s0 + per);
    for (int i = s0 + t; i < e0; i += 256) {
        unsigned ss = (unsigned)src[i];
        unsigned dd = (unsigned)dst[i];
        unsigned b = dd >> BSH;
        unsigned r = atomicAdd(&cnt[b], 1u);
        pairs[basel[b] + r] = (ss << BSH) | (dd & BMASK);
    }
}

// --------------------------- per-bucket degree histogram -> dinv ----
__global__ __launch_bounds__(512) void k_deg(const unsigned* __restrict__ pairs,
                                             const unsigned* __restrict__ boff,
                                             const unsigned* __restrict__ count,
                                             float* __restrict__ dinv, int n) {
    __shared__ unsigned h[NPB];
    int b = blockIdx.x;
    int t = threadIdx.x;
    if (t < NPB) h[t] = 0u;
    __syncthreads();
    unsigned start = boff[b];
    unsigned cnt = count[b];
    for (unsigned i = t; i < cnt; i += 512)
        atomicAdd(&h[pairs[start + i] & BMASK], 1u);
    __syncthreads();
    if (t < NPB) {
        int node = (b << BSH) + t;
        if (node < n) dinv[node] = rsqrtf((float)h[t] + 1.0f);   // +1 self-loop
    }
}

// ------------------------------------------------------------------ GEMM1 ----
// g1[row][k] = (x[row] @ W1)[k] * dinv[row]
__global__ __launch_bounds__(256) void k_gemm1(const float* __restrict__ x,
                                               const float* __restrict__ W,
                                               const float* __restrict__ dinv,
                                               float* __restrict__ g1, int n) {
    int row = blockIdx.x * 256 + threadIdx.x;
    if (row >= n) return;
    const float4* __restrict__ x4 = (const float4*)(x + (size_t)row * F_IN);
    float acc[HDIM];
#pragma unroll
    for (int k = 0; k < HDIM; ++k) acc[k] = 0.f;
#pragma unroll 2
    for (int f4 = 0; f4 < F_IN / 4; ++f4) {
        float4 xv = x4[f4];
#pragma unroll
        for (int j = 0; j < 4; ++j) {
            float xs = (&xv.x)[j];
            const float* wrow = W + (size_t)(f4 * 4 + j) * HDIM;  // wave-uniform -> scalar
#pragma unroll
            for (int k = 0; k < HDIM; ++k) acc[k] += xs * wrow[k];
        }
    }
    float di = dinv[row];
    float4* g1o = (float4*)(g1 + (size_t)row * HDIM);
#pragma unroll
    for (int k4 = 0; k4 < 4; ++k4) {
        float4 g;
        g.x = acc[k4 * 4 + 0] * di;
        g.y = acc[k4 * 4 + 1] * di;
        g.z = acc[k4 * 4 + 2] * di;
        g.w = acc[k4 * 4 + 3] * di;
        g1o[k4] = g;
    }
}

// ------------------- aggregation 1: bucket-local LDS accumulate ----
// agg1[d][k] = dinv[d] * ( g1[d][k] + sum_{s->d} g1[s][k] )
__global__ __launch_bounds__(512) void k_agg1(const unsigned* __restrict__ pairs,
                                              const unsigned* __restrict__ boff,
                                              const unsigned* __restrict__ count,
                                              const float* __restrict__ g1,
                                              const float* __restrict__ dinv,
                                              float* __restrict__ agg1, int n) {
    __shared__ float acc[NPB * HDIM];           // 16 KB
    int b = blockIdx.x;
    int t = threadIdx.x;
    for (int i = t; i < NPB * HDIM; i += 512) acc[i] = 0.f;
    __syncthreads();
    unsigned start = boff[b];
    unsigned cnt = count[b];
    int k = t & 15;
    unsigned slot = t >> 4;                     // 32 edge slots
    unsigned i = slot;
    for (; i + 32 < cnt; i += 64) {             // 2-way unroll for MLP
        unsigned pv0 = pairs[start + i];
        unsigned pv1 = pairs[start + i + 32];
        float v0 = g1[(size_t)(pv0 >> BSH) * HDIM + k];
        float v1 = g1[(size_t)(pv1 >> BSH) * HDIM + k];
        atomicAdd(&acc[(pv0 & BMASK) * HDIM + k], v0);
        atomicAdd(&acc[(pv1 & BMASK) * HDIM + k], v1);
    }
    if (i < cnt) {
        unsigned pv = pairs[start + i];
        atomicAdd(&acc[(pv & BMASK) * HDIM + k], g1[(size_t)(pv >> BSH) * HDIM + k]);
    }
    __syncthreads();
    for (int j = t; j < NPB * HDIM; j += 512) {
        int l = j >> 4;
        int node = (b << BSH) + l;
        if (node < n)
            agg1[(size_t)node * HDIM + (j & 15)] =
                (acc[j] + g1[(size_t)node * HDIM + (j & 15)]) * dinv[node];
    }
}

// ---------------------------------------------------- layer2: relu + GEMM2 ----
__global__ __launch_bounds__(256) void k_layer2(const float* __restrict__ agg1,
                                                const float* __restrict__ b1,
                                                const float* __restrict__ W2,
                                                const float* __restrict__ dinv,
                                                float* __restrict__ g2, int n) {
    int i = blockIdx.x * 256 + threadIdx.x;
    if (i >= n) return;
    float v[HDIM];
    const float4* a4 = (const float4*)(agg1 + (size_t)i * HDIM);
#pragma unroll
    for (int k4 = 0; k4 < 4; ++k4) {
        float4 t = a4[k4];
        v[k4 * 4 + 0] = fmaxf(t.x + b1[k4 * 4 + 0], 0.f);
        v[k4 * 4 + 1] = fmaxf(t.y + b1[k4 * 4 + 1], 0.f);
        v[k4 * 4 + 2] = fmaxf(t.z + b1[k4 * 4 + 2], 0.f);
        v[k4 * 4 + 3] = fmaxf(t.w + b1[k4 * 4 + 3], 0.f);
    }
    float di = dinv[i];
#pragma unroll
    for (int c = 0; c < CDIM; ++c) {
        float h = 0.f;
#pragma unroll
        for (int k = 0; k < HDIM; ++k) h += v[k] * W2[(size_t)k * CDIM + c];
        g2[(size_t)i * 8 + c] = h * di;
    }
    g2[(size_t)i * 8 + 7] = 0.f;
}

// ------- aggregation 2 + bias + logsoftmax: bucket-local LDS accumulate ----
__global__ __launch_bounds__(512) void k_agg2_out(const unsigned* __restrict__ pairs,
                                                  const unsigned* __restrict__ boff,
                                                  const unsigned* __restrict__ count,
                                                  const float* __restrict__ g2,
                                                  const float* __restrict__ dinv,
                                                  const float* __restrict__ b2,
                                                  float* __restrict__ out, int n) {
    __shared__ float acc[NPB * 8];              // 8 KB
    int b = blockIdx.x;
    int t = threadIdx.x;
    for (int i = t; i < NPB * 8; i += 512) acc[i] = 0.f;
    __syncthreads();
    unsigned start = boff[b];
    unsigned cnt = count[b];
    int k = t & 7;
    unsigned slot = t >> 3;                     // 64 edge slots
    unsigned i = slot;
    for (; i + 64 < cnt; i += 128) {            // 2-way unroll
        unsigned pv0 = pairs[start + i];
        unsigned pv1 = pairs[start + i + 64];
        float v0 = g2[(size_t)(pv0 >> BSH) * 8 + k];
        float v1 = g2[(size_t)(pv1 >> BSH) * 8 + k];
        atomicAdd(&acc[(pv0 & BMASK) * 8 + k], v0);
        atomicAdd(&acc[(pv1 & BMASK) * 8 + k], v1);
    }
    if (i < cnt) {
        unsigned pv = pairs[start + i];
        atomicAdd(&acc[(pv & BMASK) * 8 + k], g2[(size_t)(pv >> BSH) * 8 + k]);
    }
    __syncthreads();
    if (t < NPB) {
        int node = (b << BSH) + t;
        if (node < n) {
            float di = dinv[node];
            float z[CDIM];
            float m = -1e30f;
#pragma unroll
            for (int c = 0; c < CDIM; ++c) {
                z[c] = (acc[t * 8 + c] + g2[(size_t)node * 8 + c]) * di + b2[c];
                m = fmaxf(m, z[c]);
            }
            float ssum = 0.f;
#pragma unroll
            for (int c = 0; c < CDIM; ++c) ssum += expf(z[c] - m);
            float l = logf(ssum);
#pragma unroll
            for (int c = 0; c < CDIM; ++c) out[(size_t)node * CDIM + c] = z[c] - m - l;
        }
    }
}

// ---------------------------------------------------------------- launcher ----
static inline size_t align4w(size_t w) { return (w + 3) & ~(size_t)3; }

extern "C" void kernel_launch(void* const* d_in, const int* in_sizes, int n_in,
                              void* d_out, int out_size, void* d_ws, size_t ws_size,
                              hipStream_t stream) {
    const float* x  = (const float*)d_in[0];
    const int*   ei = (const int*)d_in[1];
    const float* W1 = (const float*)d_in[2];
    const float* b1 = (const float*)d_in[3];
    const float* W2 = (const float*)d_in[4];
    const float* b2 = (const float*)d_in[5];
    float* out = (float*)d_out;

    int n = in_sizes[0] / F_IN;
    int E = in_sizes[1] / 2;
    const int* src = ei;
    const int* dst = ei + E;
    int nbuck = (n + NPB - 1) >> BSH;          // 391 for n=100000 (<=512)

    int nb = (n + 255) / 256;

    // workspace layout (32-bit words, 16B-aligned regions)
    unsigned* w = (unsigned*)d_ws;
    size_t o = 0;
    unsigned* hist_g = w + o;             o += align4w((size_t)nbuck * NBLK);
    unsigned* count  = w + o;             o += align4w((size_t)nbuck);
    unsigned* boff   = w + o;             o += align4w((size_t)nbuck);
    unsigned* pairs  = w + o;             o += align4w((size_t)E);
    float*    dinv   = (float*)(w + o);   o += align4w((size_t)n);
    float*    g1     = (float*)(w + o);   o += align4w((size_t)n * HDIM);
    float*    agg1   = (float*)(w + o);   o += align4w((size_t)n * HDIM);
    float*    g2     = (float*)(w + o);   o += align4w((size_t)n * 8);

    hipLaunchKernelGGL(k_p2a,          dim3(NBLK),  dim3(512), 0, stream, dst, hist_g, E, nbuck);
    hipLaunchKernelGGL(k_scan_buckets, dim3(nbuck), dim3(256), 0, stream, hist_g, count);
    hipLaunchKernelGGL(k_scan_tot,     dim3(1),     dim3(512), 0, stream, count, boff, nbuck);
    hipLaunchKernelGGL(k_p2b,          dim3(NBLK),  dim3(256), 0, stream, src, dst, hist_g, boff, pairs, E, nbuck);
    hipLaunchKernelGGL(k_deg,          dim3(nbuck), dim3(512), 0, stream, pairs, boff, count, dinv, n);
    hipLaunchKernelGGL(k_gemm1,        dim3(nb),    dim3(256), 0, stream, x, W1, dinv, g1, n);
    hipLaunchKernelGGL(k_agg1,         dim3(nbuck), dim3(512), 0, stream, pairs, boff, count, g1, dinv, agg1, n);
    hipLaunchKernelGGL(k_layer2,       dim3(nb),    dim3(256), 0, stream, agg1, b1, W2, dinv, g2, n);
    hipLaunchKernelGGL(k_agg2_out,     dim3(nbuck), dim3(512), 0, stream, pairs, boff, count, g2, dinv, b2, out, n);
}

// Round 6
// 512.086 us; speedup vs baseline: 1.7878x; 1.7878x over previous
//
#include <hip/hip_runtime.h>
#include <math.h>

#define F_IN 512
#define HDIM 16
#define CDIM 7
#define NBLK 1024          // partition blocks for p2a/p2b
#define BSH  8             // 256 nodes per bucket
#define NPB  (1 << BSH)
#define BMASK ((1u << BSH) - 1u)

// ---------------------------------------------- pass 2a: coarse histogram ----
__global__ __launch_bounds__(512) void k_p2a(const int* __restrict__ dst,
                                             unsigned* __restrict__ hist_g,
                                             int E, int nbuck) {
    __shared__ unsigned lh[512];
    int blk = blockIdx.x;
    int t = threadIdx.x;
    lh[t] = 0u;
    __syncthreads();
    int per = (E + NBLK - 1) / NBLK;
    int s0 = blk * per;
    int e0 = min(E, s0 + per);
    for (int i = s0 + t; i < e0; i += 512)
        atomicAdd(&lh[((unsigned)dst[i]) >> BSH], 1u);
    __syncthreads();
    if (t < nbuck) hist_g[(size_t)t * NBLK + blk] = lh[t];
}

// ------------------------- scan within each bucket over the 1024 blocks ----
__global__ __launch_bounds__(256) void k_scan_buckets(unsigned* __restrict__ hist_g,
                                                      unsigned* __restrict__ count) {
    __shared__ unsigned s[256];
    int b = blockIdx.x;
    int t = threadIdx.x;
    unsigned* row = hist_g + (size_t)b * NBLK;
    unsigned h[4];
#pragma unroll
    for (int j = 0; j < 4; ++j) h[j] = row[4 * t + j];
    unsigned p = h[0] + h[1] + h[2] + h[3];
    s[t] = p;
    __syncthreads();
    for (int off = 1; off < 256; off <<= 1) {
        unsigned u = (t >= off) ? s[t - off] : 0u;
        __syncthreads();
        s[t] += u;
        __syncthreads();
    }
    unsigned run = s[t] - p;
#pragma unroll
    for (int j = 0; j < 4; ++j) { unsigned hh = h[j]; row[4 * t + j] = run; run += hh; }
    if (t == 255) count[b] = run;
}

// ------------------------------------ exclusive scan of bucket totals ----
__global__ __launch_bounds__(512) void k_scan_tot(const unsigned* __restrict__ count,
                                                  unsigned* __restrict__ boff, int nbuck) {
    __shared__ unsigned s[512];
    int t = threadIdx.x;
    unsigned v = (t < nbuck) ? count[t] : 0u;
    s[t] = v;
    __syncthreads();
    for (int off = 1; off < 512; off <<= 1) {
        unsigned u = (t >= off) ? s[t - off] : 0u;
        __syncthreads();
        s[t] += u;
        __syncthreads();
    }
    if (t < nbuck) boff[t] = s[t] - v;
}

// --------------------- pass 2b: scatter packed pairs into bucket regions ----
__global__ __launch_bounds__(512) void k_p2b(const int* __restrict__ src,
                                             const int* __restrict__ dst,
                                             const unsigned* __restrict__ hist_g, // bases now
                                             const unsigned* __restrict__ boff,
                                             unsigned* __restrict__ pairs,
                                             int E, int nbuck) {
    __shared__ unsigned basel[512];
    __shared__ unsigned cnt[512];
    int blk = blockIdx.x;
    int t = threadIdx.x;
    for (int i = t; i < nbuck; i += 512) {
        basel[i] = hist_g[(size_t)i * NBLK + blk] + boff[i];
        cnt[i] = 0u;
    }
    __syncthreads();
    int per = (E + NBLK - 1) / NBLK;
    int s0 = blk * per;
    int e0 = min(E, s0 + per);
    for (int i = s0 + t; i < e0; i += 512) {
        unsigned ss = (unsigned)src[i];
        unsigned dd = (unsigned)dst[i];
        unsigned b = dd >> BSH;
        unsigned r = atomicAdd(&cnt[b], 1u);
        pairs[basel[b] + r] = (ss << BSH) | (dd & BMASK);
    }
}

// ----------------- pass 3: per-bucket local counting sort -> CSR + dinv ----
__global__ __launch_bounds__(1024) void k_p3(const unsigned* __restrict__ pairs,
                                             const unsigned* __restrict__ boff,
                                             const unsigned* __restrict__ count,
                                             unsigned* __restrict__ csr,
                                             unsigned* __restrict__ ptr_g,
                                             unsigned* __restrict__ deg_g,
                                             float* __restrict__ dinv, int n) {
    __shared__ unsigned hist[NPB];
    __shared__ unsigned cur[NPB];
    __shared__ unsigned sc[NPB];
    int b = blockIdx.x;
    int t = threadIdx.x;
    unsigned start = boff[b];
    unsigned cnt = count[b];
    if (t < NPB) hist[t] = 0u;
    __syncthreads();
    for (unsigned i = t; i < cnt; i += 1024)
        atomicAdd(&hist[pairs[start + i] & BMASK], 1u);
    __syncthreads();
    unsigned part = 0;
    if (t < NPB) { part = hist[t]; sc[t] = part; }
    __syncthreads();
    for (int off = 1; off < NPB; off <<= 1) {
        unsigned u = 0;
        if (t < NPB && t >= off) u = sc[t - off];
        __syncthreads();
        if (t < NPB) sc[t] += u;
        __syncthreads();
    }
    if (t < NPB) {
        unsigned x = sc[t] - part;        // exclusive
        cur[t] = x;
        int node = (b << BSH) + t;
        if (node < n) {
            ptr_g[node] = start + x;
            deg_g[node] = part;
            dinv[node] = rsqrtf((float)part + 1.0f);   // +1 self-loop
        }
    }
    __syncthreads();
    for (unsigned i = t; i < cnt; i += 1024) {
        unsigned pv = pairs[start + i];
        unsigned slot = atomicAdd(&cur[pv & BMASK], 1u);
        csr[start + slot] = pv >> BSH;
    }
}

// ------------------------------------------------------------------ GEMM1 ----
// 4 waves/block; wave q computes the f-quarter [q*128, q*128+128) for 64 rows.
// W1 stays wave-uniform -> scalar-cache loads. LDS cross-wave reduce.
__global__ __launch_bounds__(256) void k_gemm1(const float* __restrict__ x,
                                               const float* __restrict__ W,
                                               const float* __restrict__ dinv,
                                               float* __restrict__ g1, int n) {
    __shared__ float sacc[256 * HDIM];            // 16 KB: [wave*64+lane][k]
    int t = threadIdx.x;
    int lane = t & 63;
    int q = __builtin_amdgcn_readfirstlane(t >> 6);
    int row = blockIdx.x * 64 + lane;
    float acc[HDIM];
#pragma unroll
    for (int k = 0; k < HDIM; ++k) acc[k] = 0.f;
    if (row < n) {
        const float4* __restrict__ x4 = (const float4*)(x + (size_t)row * F_IN) + q * 32;
#pragma unroll 4
        for (int i = 0; i < 32; ++i) {
            float4 xv = x4[i];
            const float* wr = W + (size_t)(q * 32 + i) * 4 * HDIM;  // wave-uniform
#pragma unroll
            for (int j = 0; j < 4; ++j) {
                float xs = (&xv.x)[j];
#pragma unroll
                for (int k = 0; k < HDIM; ++k) acc[k] += xs * wr[j * HDIM + k];
            }
        }
    }
    float* sa = sacc + (size_t)t * HDIM;
#pragma unroll
    for (int k = 0; k < HDIM; ++k) sa[k] = acc[k];
    __syncthreads();
    for (int idx = t; idx < 64 * HDIM; idx += 256) {
        float s = sacc[idx] + sacc[64 * HDIM + idx] + sacc[128 * HDIM + idx] + sacc[192 * HDIM + idx];
        int node = blockIdx.x * 64 + (idx >> 4);
        if (node < n) g1[(size_t)node * HDIM + (idx & 15)] = s * dinv[node];
    }
}

// -------------------------------------------------- gather 1 (wave/node) ----
__global__ __launch_bounds__(256) void k_gather1(const unsigned* __restrict__ ptr,
                                                 const unsigned* __restrict__ deg,
                                                 const unsigned* __restrict__ csr,
                                                 const float* __restrict__ g1,
                                                 const float* __restrict__ dinv,
                                                 float* __restrict__ agg1, int n) {
    int node = blockIdx.x * 4 + (threadIdx.x >> 6);
    if (node >= n) return;
    int lane = threadIdx.x & 63;
    int k = lane & 15;
    int sub = lane >> 4;
    float acc0 = (sub == 0) ? g1[(size_t)node * HDIM + k] : 0.f;   // self-loop seed
    float acc1 = 0.f;
    unsigned start = ptr[node];
    unsigned d = deg[node];
    unsigned i = sub;
    for (; i + 4 < d; i += 8) {                   // 2 independent chains
        unsigned s0 = csr[start + i];
        unsigned s1 = csr[start + i + 4];
        acc0 += g1[(size_t)s0 * HDIM + k];
        acc1 += g1[(size_t)s1 * HDIM + k];
    }
    for (; i < d; i += 4)
        acc0 += g1[(size_t)csr[start + i] * HDIM + k];
    float acc = acc0 + acc1;
    acc += __shfl_xor(acc, 16, 64);
    acc += __shfl_xor(acc, 32, 64);
    if (lane < 16) agg1[(size_t)node * HDIM + lane] = acc * dinv[node];
}

// ---------------------------------------------------- layer2: relu + GEMM2 ----
__global__ __launch_bounds__(256) void k_layer2(const float* __restrict__ agg1,
                                                const float* __restrict__ b1,
                                                const float* __restrict__ W2,
                                                const float* __restrict__ dinv,
                                                float* __restrict__ g2, int n) {
    int i = blockIdx.x * 256 + threadIdx.x;
    if (i >= n) return;
    float v[HDIM];
    const float4* a4 = (const float4*)(agg1 + (size_t)i * HDIM);
#pragma unroll
    for (int k4 = 0; k4 < 4; ++k4) {
        float4 t = a4[k4];
        v[k4 * 4 + 0] = fmaxf(t.x + b1[k4 * 4 + 0], 0.f);
        v[k4 * 4 + 1] = fmaxf(t.y + b1[k4 * 4 + 1], 0.f);
        v[k4 * 4 + 2] = fmaxf(t.z + b1[k4 * 4 + 2], 0.f);
        v[k4 * 4 + 3] = fmaxf(t.w + b1[k4 * 4 + 3], 0.f);
    }
    float di = dinv[i];
#pragma unroll
    for (int c = 0; c < CDIM; ++c) {
        float h = 0.f;
#pragma unroll
        for (int k = 0; k < HDIM; ++k) h += v[k] * W2[(size_t)k * CDIM + c];
        g2[(size_t)i * 8 + c] = h * di;
    }
    g2[(size_t)i * 8 + 7] = 0.f;   // gather2 lane k=7 reads it
}

// ------------------------- gather 2 + bias + logsoftmax (fused, wave/node) ----
__global__ __launch_bounds__(256) void k_gather2_out(const unsigned* __restrict__ ptr,
                                                     const unsigned* __restrict__ deg,
                                                     const unsigned* __restrict__ csr,
                                                     const float* __restrict__ g2,
                                                     const float* __restrict__ dinv,
                                                     const float* __restrict__ b2,
                                                     float* __restrict__ out, int n) {
    int node = blockIdx.x * 4 + (threadIdx.x >> 6);
    if (node >= n) return;
    int lane = threadIdx.x & 63;
    int k = lane & 7;
    int sub = lane >> 3;
    float acc0 = (sub == 0) ? g2[(size_t)node * 8 + k] : 0.f;
    float acc1 = 0.f;
    unsigned start = ptr[node];
    unsigned d = deg[node];
    unsigned i = sub;
    for (; i + 8 < d; i += 16) {
        unsigned s0 = csr[start + i];
        unsigned s1 = csr[start + i + 8];
        acc0 += g2[(size_t)s0 * 8 + k];
        acc1 += g2[(size_t)s1 * 8 + k];
    }
    for (; i < d; i += 8)
        acc0 += g2[(size_t)csr[start + i] * 8 + k];
    float acc = acc0 + acc1;
    acc += __shfl_xor(acc, 8, 64);
    acc += __shfl_xor(acc, 16, 64);
    acc += __shfl_xor(acc, 32, 64);
    float z = (k < CDIM) ? acc * dinv[node] + b2[k] : -1e30f;
    float m = z;
    m = fmaxf(m, __shfl_xor(m, 1, 64));
    m = fmaxf(m, __shfl_xor(m, 2, 64));
    m = fmaxf(m, __shfl_xor(m, 4, 64));
    float ex = (k < CDIM) ? expf(z - m) : 0.f;
    float ssum = ex;
    ssum += __shfl_xor(ssum, 1, 64);
    ssum += __shfl_xor(ssum, 2, 64);
    ssum += __shfl_xor(ssum, 4, 64);
    if (lane < CDIM) out[(size_t)node * CDIM + lane] = z - m - logf(ssum);
}

// ---------------------------------------------------------------- launcher ----
static inline size_t align4w(size_t w) { return (w + 3) & ~(size_t)3; }

extern "C" void kernel_launch(void* const* d_in, const int* in_sizes, int n_in,
                              void* d_out, int out_size, void* d_ws, size_t ws_size,
                              hipStream_t stream) {
    const float* x  = (const float*)d_in[0];
    const int*   ei = (const int*)d_in[1];
    const float* W1 = (const float*)d_in[2];
    const float* b1 = (const float*)d_in[3];
    const float* W2 = (const float*)d_in[4];
    const float* b2 = (const float*)d_in[5];
    float* out = (float*)d_out;

    int n = in_sizes[0] / F_IN;
    int E = in_sizes[1] / 2;
    const int* src = ei;
    const int* dst = ei + E;
    int nbuck = (n + NPB - 1) >> BSH;          // 391 for n=100000 (<=512)

    int nb = (n + 255) / 256;
    int gemb = (n + 63) / 64;
    int gb = (n + 3) / 4;

    // workspace layout (32-bit words, 16B-aligned regions)
    unsigned* w = (unsigned*)d_ws;
    size_t o = 0;
    unsigned* hist_g = w + o;             o += align4w((size_t)nbuck * NBLK);
    unsigned* count  = w + o;             o += align4w((size_t)nbuck);
    unsigned* boff   = w + o;             o += align4w((size_t)nbuck);
    unsigned* pairs  = w + o;             o += align4w((size_t)E);
    unsigned* csr    = w + o;             o += align4w((size_t)E);
    unsigned* ptr    = w + o;             o += align4w((size_t)n);
    unsigned* deg    = w + o;             o += align4w((size_t)n);
    float*    dinv   = (float*)(w + o);   o += align4w((size_t)n);
    float*    g1     = (float*)(w + o);   o += align4w((size_t)n * HDIM);
    float*    agg1   = (float*)(w + o);   o += align4w((size_t)n * HDIM);
    float*    g2     = (float*)(w + o);   o += align4w((size_t)n * 8);

    hipLaunchKernelGGL(k_p2a,          dim3(NBLK),  dim3(512),  0, stream, dst, hist_g, E, nbuck);
    hipLaunchKernelGGL(k_scan_buckets, dim3(nbuck), dim3(256),  0, stream, hist_g, count);
    hipLaunchKernelGGL(k_scan_tot,     dim3(1),     dim3(512),  0, stream, count, boff, nbuck);
    hipLaunchKernelGGL(k_p2b,          dim3(NBLK),  dim3(512),  0, stream, src, dst, hist_g, boff, pairs, E, nbuck);
    hipLaunchKernelGGL(k_p3,           dim3(nbuck), dim3(1024), 0, stream, pairs, boff, count, csr, ptr, deg, dinv, n);
    hipLaunchKernelGGL(k_gemm1,        dim3(gemb),  dim3(256),  0, stream, x, W1, dinv, g1, n);
    hipLaunchKernelGGL(k_gather1,      dim3(gb),    dim3(256),  0, stream, ptr, deg, csr, g1, dinv, agg1, n);
    hipLaunchKernelGGL(k_layer2,       dim3(nb),    dim3(256),  0, stream, agg1, b1, W2, dinv, g2, n);
    hipLaunchKernelGGL(k_gather2_out,  dim3(gb),    dim3(256),  0, stream, ptr, deg, csr, g2, dinv, b2, out, n);
}